// Round 18
// baseline (10808.356 us; speedup 1.0000x reference)
//
#include <hip/hip_runtime.h>
#include <math.h>

#define B 512
#define S 256
#define D 64
#define H 512
#define BH (B*H)
#define KSTEPS 8

// ws floats: h 2 slots @0 | c 1 slot @2BH | xatt @3BH | flags(uint) @3BH+B*D
#define HBUF_OFF 0
#define CBUF_OFF (2*BH)
#define XATT_OFF (3*BH)
#define FLAGS_OFF (3*BH + B*D)
#define NFLAGS 1024

#define WAIT_VM0 asm volatile("s_waitcnt vmcnt(0)" ::: "memory")

__device__ __forceinline__ void ldg_sc(float4& r, const float* p) {
    asm volatile("global_load_dwordx4 %0, %1, off sc0 sc1" : "=v"(r) : "v"(p));
}
__device__ __forceinline__ void st_sc(float* p, float v) {
    asm volatile("global_store_dword %0, %1, off sc0 sc1" :: "v"(p), "v"(v));
}
__device__ __forceinline__ void waitf(unsigned int* f, unsigned int tgt) {
    if (threadIdx.x == 0) {
        unsigned int spin = 0;
        while (__hip_atomic_load(f, __ATOMIC_RELAXED, __HIP_MEMORY_SCOPE_AGENT) < tgt) {
            __builtin_amdgcn_s_sleep(2);
            if (++spin > (1u << 18)) break;   // finite bail: no hang
        }
    }
    __syncthreads();
}
__device__ __forceinline__ void bumpf(unsigned int* f) {
    __hip_atomic_fetch_add(f, 1u, __ATOMIC_RELAXED, __HIP_MEMORY_SCOPE_AGENT);
}

__global__ __launch_bounds__(256) void init_zero(float* __restrict__ ws) {
    int i = blockIdx.x * blockDim.x + threadIdx.x;
    if (i < BH) {
        ws[HBUF_OFF + i] = 0.f;   // h slot 0
        ws[CBUF_OFF + i] = 0.f;   // c
    }
    if (i < NFLAGS) ((unsigned int*)(ws + FLAGS_OFF))[i] = 0u;
}

// Fused 8-step kernel. 512 blocks, duty by PARITY (bid&1): even = attn
// (2 rows each), odd = gates (32 rows x 32 units, R2 tile). Parity ensures
// sequential CU fill pairs 1 attn + 1 gates per CU. All co-resident
// (66KB LDS -> 2 blocks/CU). State via sc0sc1; weights normal cached loads.
__global__ __launch_bounds__(256, 2) void fused_kernel(
    const float* __restrict__ x, const float* __restrict__ Wa,
    const float* __restrict__ Ua, const float* __restrict__ ba,
    const float* __restrict__ Va,
    const float* __restrict__ Wih, const float* __restrict__ Whh,
    const float* __restrict__ bih, const float* __restrict__ bhh,
    float* __restrict__ ws, int base)
{
    const int bid = blockIdx.x;
    const int tid = threadIdx.x;
    float* h32 = ws + HBUF_OFF;
    float* c32 = ws + CBUF_OFF;
    float* xatt = ws + XATT_OFF;
    unsigned int* flags = (unsigned int*)(ws + FLAGS_OFF);

    __shared__ float h_act[2][32][68];   // gates act dbuf  17.4 KB
    __shared__ float w_lds[4][32][68];   // gates W tile    34.8 KB
    __shared__ float c_t[32][36];        // gates c tile     4.6 KB
    __shared__ float h2[2][512];         // attn h rows      4.0 KB
    __shared__ float c2[2][512];         // attn c rows      4.0 KB
    __shared__ float part[2][2][64];
    __shared__ float ta[2][64];
    __shared__ float pv[2][2][64];

    const int id = bid >> 1;

    if ((bid & 1) == 0) {
        // ======================= attn duty =======================
        const int d = tid & 63;
        const int rr = (tid >> 6) & 1;
        const int p = tid >> 7;
        const int r_t = id >> 4;                  // row-tile 0..15
        const int brow = id * 2 + rr;
        unsigned int* hf = flags + r_t * 32;
        unsigned int* xf = flags + 512 + r_t * 32;

        for (int sub = 0; sub < KSTEPS; ++sub) {
            const int ts = base + sub;
            const int rd = ts & 1;
            waitf(hf, 16u * (unsigned int)ts);    // h(ts), c(ts) published

            {   // stage own 2 rows of h and c into LDS (sc)
                float4 hv, cv;
                const int row = id * 2 + (tid >> 7);
                ldg_sc(hv, h32 + (size_t)rd * BH + (size_t)row * H + (tid & 127) * 4);
                ldg_sc(cv, c32 + (size_t)row * H + (tid & 127) * 4);
                WAIT_VM0;
                *(float4*)&h2[tid >> 7][(tid & 127) * 4] = hv;
                *(float4*)&c2[tid >> 7][(tid & 127) * 4] = cv;
            }
            __syncthreads();

            const float* __restrict__ xrow = x + ((size_t)brow * S + ts) * D;
            float a = 0.f;
            if (p == 0) {
                a = ba[d];
                #pragma unroll 8
                for (int k = 0; k < D; ++k) a += xrow[k] * Wa[k*D + d];
                #pragma unroll 8
                for (int k = 0; k < H; ++k) a += h2[rr][k] * Ua[k*D + d];
            } else {
                #pragma unroll 8
                for (int k = 0; k < H; ++k) a += c2[rr][k] * Ua[(size_t)(H + k)*D + d];
            }
            part[rr][p][d] = a;
            __syncthreads();
            if (p == 0) ta[rr][d] = tanhf(part[rr][0][d] + part[rr][1][d]);
            __syncthreads();
            float av = 0.f;
            {
                const int k0 = p * 32;
                #pragma unroll 8
                for (int k = k0; k < k0 + 32; ++k) av += ta[rr][k] * Va[k*D + d];
            }
            pv[rr][p][d] = av;
            __syncthreads();
            float v = pv[rr][0][d] + pv[rr][1][d];
            float m = v;
            #pragma unroll
            for (int o = 32; o > 0; o >>= 1) m = fmaxf(m, __shfl_xor(m, o));
            float e = expf(v - m);
            float ssum = e;
            #pragma unroll
            for (int o = 32; o > 0; o >>= 1) ssum += __shfl_xor(ssum, o);
            if (p == 0) {
                st_sc(xatt + (size_t)brow * D + d, (e / ssum) * xrow[d]);
            }
            WAIT_VM0;
            __syncthreads();
            if (tid == 0) bumpf(xf);
        }
    } else {
        // ======================= gates duty =======================
        const int g = id;
        const int u_t = g & 15, r_t = g >> 4;
        const int u0 = u_t * 32, r0 = r_t * 32;
        const int tm = tid & 7, tn = tid >> 3;
        const int u = u0 + tn;
        unsigned int* hf = flags + r_t * 32;
        unsigned int* xf = flags + 512 + r_t * 32;

        const float bs0 = bih[0*H + u] + bhh[0*H + u];
        const float bs1 = bih[1*H + u] + bhh[1*H + u];
        const float bs2 = bih[2*H + u] + bhh[2*H + u];
        const float bs3 = bih[3*H + u] + bhh[3*H + u];

        const int f0 = tid & 15, rl0 = tid >> 4;
        const int f1 = (tid + 256) & 15, rl1 = (tid + 256) >> 4;

        for (int sub = 0; sub < KSTEPS; ++sub) {
            const int ts = base + sub;
            const int rd = ts & 1, wrs = rd ^ 1;
            waitf(hf, 16u * (unsigned int)ts);    // h(ts), c(ts) published

            float acc[4][4];
            #pragma unroll
            for (int i = 0; i < 4; ++i)
                #pragma unroll
                for (int q = 0; q < 4; ++q) acc[i][q] = 0.f;

            // prologue: issue act(0) + c tile loads (sc, no wait)
            float4 pa0, pa1, ctv;
            {
                const float* hb = h32 + (size_t)rd * BH;
                ldg_sc(pa0, hb + (size_t)(r0 + rl0)*H + f0*4);
                ldg_sc(pa1, hb + (size_t)(r0 + rl1)*H + f1*4);
                ldg_sc(ctv, c32 + (size_t)(r0 + (tid >> 3))*H + u0 + (tid & 7)*4);
            }

            for (int kb = 0; kb < 9; ++kb) {
                __syncthreads();             // prev compute done; w_lds free
                {   // W stage (normal cached loads)
                    const float* src; int ldsrc, kofs;
                    if (kb < 8) { src = Whh; ldsrc = H; kofs = kb*64; }
                    else        { src = Wih; ldsrc = D; kofs = 0; }
                    #pragma unroll
                    for (int it = 0; it < 8; ++it) {
                        int j = tid + it*256;
                        int f4c = j & 15, row = j >> 4;
                        int uu = row & 31, q = row >> 5;
                        float4 v = *(const float4*)(src + (size_t)(q*H + u0 + uu)*ldsrc + kofs + f4c*4);
                        *(float4*)&w_lds[q][uu][f4c*4] = v;
                    }
                }
                if (kb == 8) {               // xatt(ts) needed now
                    waitf(xf, 16u * (unsigned int)(ts + 1));
                    ldg_sc(pa0, xatt + (size_t)(r0 + rl0)*D + f0*4);
                    ldg_sc(pa1, xatt + (size_t)(r0 + rl1)*D + f1*4);
                }
                WAIT_VM0;                    // act regs landed (issued last chunk)
                *(float4*)&h_act[kb & 1][rl0][f0*4] = pa0;
                *(float4*)&h_act[kb & 1][rl1][f1*4] = pa1;
                if (kb == 0)
                    *(float4*)&c_t[tid >> 3][(tid & 7)*4] = ctv;
                __syncthreads();
                if (kb < 7) {                // prefetch act(kb+1) under compute
                    const float* hb = h32 + (size_t)rd * BH;
                    ldg_sc(pa0, hb + (size_t)(r0 + rl0)*H + (kb + 1)*64 + f0*4);
                    ldg_sc(pa1, hb + (size_t)(r0 + rl1)*H + (kb + 1)*64 + f1*4);
                }
                const int cb = kb & 1;
                #pragma unroll
                for (int k4 = 0; k4 < 16; ++k4) {
                    float4 wv[4], hv[4];
                    #pragma unroll
                    for (int q = 0; q < 4; ++q)
                        wv[q] = *(const float4*)&w_lds[q][tn][k4*4];
                    #pragma unroll
                    for (int i = 0; i < 4; ++i)
                        hv[i] = *(const float4*)&h_act[cb][tm + 8*i][k4*4];
                    #pragma unroll
                    for (int i = 0; i < 4; ++i)
                        #pragma unroll
                        for (int q = 0; q < 4; ++q) {
                            acc[i][q] = fmaf(hv[i].x, wv[q].x, acc[i][q]);
                            acc[i][q] = fmaf(hv[i].y, wv[q].y, acc[i][q]);
                            acc[i][q] = fmaf(hv[i].z, wv[q].z, acc[i][q]);
                            acc[i][q] = fmaf(hv[i].w, wv[q].w, acc[i][q]);
                        }
                }
            }

            // LSTM update + publish h(ts+1), c(ts+1) via sc
            float* __restrict__ hW = h32 + (size_t)wrs * BH;
            #pragma unroll
            for (int i = 0; i < 4; ++i) {
                const int b = r0 + tm + 8*i;
                float gi = acc[i][0] + bs0;
                float gf = acc[i][1] + bs1;
                float gg = acc[i][2] + bs2;
                float go = acc[i][3] + bs3;
                float c_old = c_t[tm + 8*i][tn];
                float si = 1.f / (1.f + expf(-gi));
                float sf = 1.f / (1.f + expf(-gf));
                float so = 1.f / (1.f + expf(-go));
                float cn = sf * c_old + si * tanhf(gg);
                float hn = so * tanhf(cn);
                st_sc(c32 + (size_t)b * H + u, cn);
                st_sc(hW + (size_t)b * H + u, hn);
            }
            WAIT_VM0;
            __syncthreads();
            if (tid == 0) bumpf(hf);
        }
    }
}

__global__ __launch_bounds__(256) void fc_kernel(
    const float* __restrict__ fcw, const float* __restrict__ fcb,
    const float* __restrict__ ws, float* __restrict__ out)
{
    const int b = blockIdx.x;
    __shared__ float hrow[H];
    const float* __restrict__ hp = ws + HBUF_OFF + (size_t)b*H;  // final h in slot 0
    for (int k = threadIdx.x; k < H; k += 256) hrow[k] = hp[k];
    __syncthreads();
    int j = threadIdx.x;
    if (j < 24) {
        float a = fcb[j];
        #pragma unroll 8
        for (int k = 0; k < H; ++k) a += hrow[k] * fcw[j*H + k];
        out[b*24 + j] = a;
    }
}

extern "C" void kernel_launch(void* const* d_in, const int* in_sizes, int n_in,
                              void* d_out, int out_size, void* d_ws, size_t ws_size,
                              hipStream_t stream) {
    const float* x   = (const float*)d_in[0];
    const float* Wa  = (const float*)d_in[1];
    const float* Ua  = (const float*)d_in[2];
    const float* ba  = (const float*)d_in[3];
    const float* Va  = (const float*)d_in[4];
    const float* Wih = (const float*)d_in[5];
    const float* Whh = (const float*)d_in[6];
    const float* bih = (const float*)d_in[7];
    const float* bhh = (const float*)d_in[8];
    const float* fcw = (const float*)d_in[9];
    const float* fcb = (const float*)d_in[10];
    float* out = (float*)d_out;
    float* ws  = (float*)d_ws;

    hipLaunchKernelGGL(init_zero, dim3((BH + 255)/256), dim3(256), 0, stream, ws);
    for (int base = 0; base < S; base += KSTEPS) {
        hipLaunchKernelGGL(fused_kernel, dim3(512), dim3(256), 0, stream,
                           x, Wa, Ua, ba, Va, Wih, Whh, bih, bhh, ws, base);
    }
    hipLaunchKernelGGL(fc_kernel, dim3(B), dim3(256), 0, stream, fcw, fcb, ws, out);
}